// Round 5
// baseline (284.818 us; speedup 1.0000x reference)
//
#include <hip/hip_runtime.h>
#include <hip/hip_bf16.h>

#define SEQ 2048
#define DMODEL 1024
#define NHEAD 16
#define HDIM 64
#define DPOS 64
#define BATCH 2

constexpr float EVENT_HORIZON = 1e-6f;
constexpr float MAX_FORCE = 50.0f;
constexpr float CURV = 0.15f;
constexpr float LOG2E = 1.44269504f;
// P = exp2(min(f,50)*log2e - S2), S2 = 39*log2e: e <= 2^15.87 = 59847 (fp16-safe),
// ratio-invariant under softmax normalization.
constexpr float SHIFT = 39.0f;

typedef __attribute__((ext_vector_type(8))) short frag8;        // 8 bf16/ushort
typedef __attribute__((ext_vector_type(4))) unsigned int uint4v;
typedef __attribute__((ext_vector_type(8))) _Float16 half8;     // 8 fp16
typedef __attribute__((ext_vector_type(2))) _Float16 half2t;    // 2 fp16
typedef __attribute__((ext_vector_type(4))) float frag4f;       // 4 fp32 (C/D)

union A8u { half8 v; half2t h[4]; };

__device__ inline short bfbits(float f) {
  __hip_bfloat16 h = __float2bfloat16(f);
  return *reinterpret_cast<short*>(&h);
}
__device__ inline float fbits(unsigned u) {
  union { unsigned u; float f; } c; c.u = u; return c.f;
}
__device__ inline half2t pkrtz(float a, float b) {
  return __builtin_bit_cast(half2t, __builtin_amdgcn_cvt_pkrtz(a, b));
}
// native 2^x, single v_exp_f32 (no hidden *log2e mul like __expf)
__device__ inline float exp2_fast(float x) {
  float r;
  asm("v_exp_f32 %0, %1" : "=v"(r) : "v"(x));
  return r;
}
// XOR swizzle in 16B units: row = 8 units (128B); b128 frag reads (fixed unit,
// 16 consecutive rows) and staging writes both cover banks <=2-way (free).
__device__ inline int swz(int row, int u) { return row * 8 + (u ^ (row & 7)); }

// ---------------------------------------------------------------------------
// Prep A (fused): transpose x -> xt[bh][d][j] fp16 AND masses[bh][s] =
// softplus(dot(x_row, W_mass[h])).
// ---------------------------------------------------------------------------
__global__ __launch_bounds__(256) void prep_xt_masses(
    const float* __restrict__ x, const float* __restrict__ Wm,
    _Float16* __restrict__ xt, float* __restrict__ masses) {
  int bh = blockIdx.x;           // b*16+h
  int h = bh & 15, b = bh >> 4;
  int t = threadIdx.x;
  int d = t & 63;
  int jg = (t >> 6) + (blockIdx.y << 2);   // j-group of 8, 0..255
  int j0 = jg * 8;
  const float* src = x + (size_t)(b * SEQ) * DMODEL + h * HDIM + d;
  float wmd = Wm[h * HDIM + d];
  half8 v;
  float fv[8];
#pragma unroll
  for (int jj = 0; jj < 8; ++jj) {
    float f = src[(size_t)(j0 + jj) * DMODEL];
    fv[jj] = f;
    v[jj] = (_Float16)f;
  }
  *(half8*)(xt + ((size_t)bh * HDIM + d) * SEQ + j0) = v;

  float msum = 0.f;
#pragma unroll
  for (int jj = 0; jj < 8; ++jj) {
    float s = fv[jj] * wmd;
#pragma unroll
    for (int off = 32; off; off >>= 1) s += __shfl_xor(s, off, 64);
    if (d == jj) msum = s;      // lane jj keeps row j0+jj's dot
  }
  if (d < 8) {
    float m = (msum > 20.f) ? msum : log1pf(expf(msum));
    masses[(size_t)bh * SEQ + j0 + d] = m;
  }
}

// ---------------------------------------------------------------------------
// Kernel 2: LDS-tiled distance kernel, bf16 output.
// ---------------------------------------------------------------------------
__global__ __launch_bounds__(256) void invdist_kernel(
    const float* __restrict__ pos, unsigned short* __restrict__ invd) {
  __shared__ float Li[64 * 68];
  __shared__ float Lj[64 * 68];
  int t = threadIdx.x;
  int i0 = blockIdx.y * 64, j0 = blockIdx.x * 64;

  int kk = (t & 15) * 4;
  int rr = t >> 4;
#pragma unroll
  for (int q = 0; q < 4; ++q) {
    int row = q * 16 + rr;
    float4 a = *(const float4*)(pos + (size_t)(i0 + row) * DPOS + kk);
    float4 b = *(const float4*)(pos + (size_t)(j0 + row) * DPOS + kk);
    Li[(kk + 0) * 68 + row] = a.x; Li[(kk + 1) * 68 + row] = a.y;
    Li[(kk + 2) * 68 + row] = a.z; Li[(kk + 3) * 68 + row] = a.w;
    Lj[(kk + 0) * 68 + row] = b.x; Lj[(kk + 1) * 68 + row] = b.y;
    Lj[(kk + 2) * 68 + row] = b.z; Lj[(kk + 3) * 68 + row] = b.w;
  }
  __syncthreads();

  int ti = (t >> 4) * 4;
  int tj = (t & 15) * 4;

  float acc[4][4];
#pragma unroll
  for (int a = 0; a < 4; ++a)
#pragma unroll
    for (int b = 0; b < 4; ++b) acc[a][b] = 0.f;

#pragma unroll 8
  for (int k = 0; k < 64; ++k) {
    float4 a = *(const float4*)(&Li[k * 68 + ti]);
    float4 b = *(const float4*)(&Lj[k * 68 + tj]);
    float av[4] = {a.x, a.y, a.z, a.w};
    float bv[4] = {b.x, b.y, b.z, b.w};
#pragma unroll
    for (int mi = 0; mi < 4; ++mi)
#pragma unroll
      for (int mj = 0; mj < 4; ++mj) {
        float d = av[mi] - bv[mj];
        acc[mi][mj] += d * d;
      }
  }

#pragma unroll
  for (int mi = 0; mi < 4; ++mi) {
    ushort4 o;
    unsigned short* op = (unsigned short*)&o;
#pragma unroll
    for (int mj = 0; mj < 4; ++mj) {
      float d2 = acc[mi][mj];
      float dn = sqrtf(d2 + EVENT_HORIZON);
      float w = d2 * (1.f + CURV * __cosf(dn));
      op[mj] = (unsigned short)bfbits(1.0f / fmaxf(w, EVENT_HORIZON));
    }
    *(ushort4*)(&invd[(size_t)(i0 + ti + mi) * SEQ + j0 + tj]) = o;
  }
}

// ---------------------------------------------------------------------------
// Kernel 3: fused gravitational attention, fp16 MFMA PV.
// r5: r4 structure (256 thr = 4 waves x 16 i-rows, grid 1024 XCD-clustered)
// with per-chunk machinery stripped: chunk loop unrolled x2 so the LDS
// buffer index is compile-time (no runtime selects), masses back to
// REGISTER prefetch (r1-style; removes the Ms LDS round trip from the
// chunk-start critical path; 16 same-addr lanes -> L1 broadcast).
// launch_bounds(256,6) caps VGPR at 85 (~65 needed -> no spill).
// ---------------------------------------------------------------------------
__global__ __launch_bounds__(256, 6) void attn_mfma_kernel(
    const _Float16* __restrict__ xt, const float* __restrict__ masses,
    const unsigned short* __restrict__ invd, const float* __restrict__ G,
    _Float16* __restrict__ attnout) {
  __shared__ _Float16 Vs[2][64 * 64];   // [buf], 8 KB each, XOR-swizzled

  constexpr float S2 = SHIFT * LOG2E;                 // 56.265
  constexpr float C2 = (MAX_FORCE - SHIFT) * LOG2E;   // 15.870

  int bid = blockIdx.x;
  int bh = (bid & 7) * 4 + ((bid >> 3) & 3);   // XCD-clustered: 4 bh per XCD
  int iblk = bid >> 5;
  int h = bh & (NHEAD - 1), b = bh >> 4;
  int i0 = iblk * 64;
  int t = threadIdx.x, w = t >> 6, lane = t & 63;
  int l15 = lane & 15, quad = lane >> 4;
  int iw = i0 + w * 16;

  float gabs = fabsf(G[h]);
  const float* mrow = masses + (size_t)bh * SEQ;
  float cm = gabs * mrow[iw + l15] * LOG2E;           // row scalar, log2 domain
  const unsigned short* ivrow = invd + (size_t)(iw + l15) * SEQ;
  const float* mjp = mrow + quad * 8;                 // masses gather base

  // staging role: thread t -> d-row t>>2, 16B-units {2*(t&3), 2*(t&3)+1}
  int srow = t >> 2, sunit = (t & 3) * 2;
  const _Float16* srcrow =
      xt + ((size_t)bh * HDIM + srow) * SEQ + sunit * 8;
  int swzoff0 = swz(srow, sunit) * 8;
  int swzoff1 = swz(srow, sunit + 1) * 8;

  half8 vone;
#pragma unroll
  for (int k = 0; k < 8; ++k) vone[k] = (_Float16)1.f;

  frag4f acc[4];
#pragma unroll
  for (int nt = 0; nt < 4; ++nt) acc[nt] = (frag4f)0.f;
  frag4f accs = (frag4f)0.f;          // row sums (every column identical)

  // ---- prologue: chunk 0 ----
  *(half8*)(&Vs[0][0] + swzoff0) = *(const half8*)(srcrow);
  *(half8*)(&Vs[0][0] + swzoff1) = *(const half8*)(srcrow + 8);
  frag8 iv_cur[2], iv_nxt[2];
  float4 mj_cur[4], mj_nxt[4];
  iv_cur[0] = *(const frag8*)(ivrow + quad * 8);
  iv_cur[1] = *(const frag8*)(ivrow + 32 + quad * 8);
  mj_cur[0] = *(const float4*)(mjp);
  mj_cur[1] = *(const float4*)(mjp + 4);
  mj_cur[2] = *(const float4*)(mjp + 32);
  mj_cur[3] = *(const float4*)(mjp + 36);
  __syncthreads();

  for (int cc = 0; cc < 16; ++cc) {
#pragma unroll
    for (int u = 0; u < 2; ++u) {
      int c = cc * 2 + u;               // buf index u is compile-time
      // ---- issue prefetches for chunk c+1 ----
      half8 vpre0, vpre1;
      if (c < 31) {
        int jn = (c + 1) * 64;
        vpre0 = *(const half8*)(srcrow + jn);
        vpre1 = *(const half8*)(srcrow + jn + 8);
        iv_nxt[0] = *(const frag8*)(ivrow + jn + quad * 8);
        iv_nxt[1] = *(const frag8*)(ivrow + jn + 32 + quad * 8);
        mj_nxt[0] = *(const float4*)(mjp + jn);
        mj_nxt[1] = *(const float4*)(mjp + jn + 4);
        mj_nxt[2] = *(const float4*)(mjp + jn + 32);
        mj_nxt[3] = *(const float4*)(mjp + jn + 36);
      }

      // ---- compute chunk c from buf[u] ----
      const _Float16* Vbase = &Vs[u][0];
#pragma unroll
      for (int kh = 0; kh < 2; ++kh) {
        float mjf[8] = {mj_cur[kh * 2].x, mj_cur[kh * 2].y,
                        mj_cur[kh * 2].z, mj_cur[kh * 2].w,
                        mj_cur[kh * 2 + 1].x, mj_cur[kh * 2 + 1].y,
                        mj_cur[kh * 2 + 1].z, mj_cur[kh * 2 + 1].w};
        uint4v uv = __builtin_bit_cast(uint4v, iv_cur[kh]);
        float e[8];
#pragma unroll
        for (int p = 0; p < 4; ++p) {
          float ivA = fbits(uv[p] << 16);          // even j: low bf16
          float ivB = fbits(uv[p] & 0xffff0000u);  // odd j: high bf16
          float fA = fmaf(cm * mjf[2 * p], ivA, -S2);
          float fB = fmaf(cm * mjf[2 * p + 1], ivB, -S2);
          e[2 * p] = exp2_fast(fminf(fA, C2));
          e[2 * p + 1] = exp2_fast(fminf(fB, C2));
        }
        A8u A;
#pragma unroll
        for (int p = 0; p < 4; ++p)
          A.h[p] = pkrtz(e[2 * p], e[2 * p + 1]);

        __builtin_amdgcn_s_setprio(1);
        accs = __builtin_amdgcn_mfma_f32_16x16x32_f16(A.v, vone, accs, 0, 0, 0);
#pragma unroll
        for (int nt = 0; nt < 4; ++nt) {
          half8 Bf = *(const half8*)(Vbase + swz(nt * 16 + l15, kh * 4 + quad) * 8);
          acc[nt] = __builtin_amdgcn_mfma_f32_16x16x32_f16(A.v, Bf, acc[nt], 0, 0, 0);
        }
        __builtin_amdgcn_s_setprio(0);
      }

      // ---- rotate prefetches in; write V prefetch to other buffer ----
      if (c < 31) {
        _Float16* Vn = &Vs[u ^ 1][0];
        *(half8*)(Vn + swzoff0) = vpre0;
        *(half8*)(Vn + swzoff1) = vpre1;
        iv_cur[0] = iv_nxt[0]; iv_cur[1] = iv_nxt[1];
        mj_cur[0] = mj_nxt[0]; mj_cur[1] = mj_nxt[1];
        mj_cur[2] = mj_nxt[2]; mj_cur[3] = mj_nxt[3];
      }
      __syncthreads();
    }
  }

  // ---- normalize + store (accs[reg] already holds row r = quad*4+reg) ----
#pragma unroll
  for (int reg = 0; reg < 4; ++reg) {
    int r = quad * 4 + reg;            // C/D row within 16x16 tile
    float s = 1.f / accs[reg];
#pragma unroll
    for (int nt = 0; nt < 4; ++nt) {
      attnout[(size_t)(b * SEQ + iw + r) * DMODEL + h * HDIM + nt * 16 + l15] =
          (_Float16)(acc[nt][reg] * s);
    }
  }
}

// ---------------------------------------------------------------------------
// Kernel 4: out = attnout @ Wout^T via fp16 MFMA, Wout converted f32->fp16
// on the fly during B-staging (RTN scalar casts, numerically identical to
// the old prep_wh). 128(M)x64(N) tile, BK=64, double-buffered swizzled LDS,
// unroll-2 K loop (compile-time buffer selects), setprio around MFMA
// cluster. grid (16,32) = 512 blocks.
// ---------------------------------------------------------------------------
__global__ __launch_bounds__(256) void out_gemm_mfma(
    const _Float16* __restrict__ Ag, const float* __restrict__ Wout,
    float* __restrict__ C) {
  __shared__ _Float16 As[2][128 * 64];   // 16 KB each
  __shared__ _Float16 Bs[2][64 * 64];    // 8 KB each

  int t = threadIdx.x, w = t >> 6, lane = t & 63;
  int l15 = lane & 15, quad = lane >> 4;
  int m0 = blockIdx.y * 128, n0 = blockIdx.x * 64;
  int mh = (w & 1) * 64, nh = (w >> 1) * 32;

  int ar = t >> 1;  int aku = (t & 1) * 4;
  int br = t >> 2;  int bku = (t & 3) * 2;
  const _Float16* abase = Ag + (size_t)(m0 + ar) * DMODEL + aku * 8;
  const float*    wbase = Wout + (size_t)(n0 + br) * DMODEL + bku * 8;

  frag4f acc[4][2];
#pragma unroll
  for (int mt = 0; mt < 4; ++mt)
#pragma unroll
    for (int nt = 0; nt < 2; ++nt) acc[mt][nt] = (frag4f)0.f;

  half8 a0, a1, a2, a3, b0, b1;
  a0 = *(const half8*)(abase);      a1 = *(const half8*)(abase + 8);
  a2 = *(const half8*)(abase + 16); a3 = *(const half8*)(abase + 24);
  {
    float4 w0 = *(const float4*)(wbase);      float4 w1 = *(const float4*)(wbase + 4);
    float4 w2 = *(const float4*)(wbase + 8);  float4 w3 = *(const float4*)(wbase + 12);
    b0[0] = (_Float16)w0.x; b0[1] = (_Float16)w0.y; b0[2] = (_Float16)w0.z; b0[3] = (_Float16)w0.w;
    b0[4] = (_Float16)w1.x; b0[5] = (_Float16)w1.y; b0[6] = (_Float16)w1.z; b0[7] = (_Float16)w1.w;
    b1[0] = (_Float16)w2.x; b1[1] = (_Float16)w2.y; b1[2] = (_Float16)w2.z; b1[3] = (_Float16)w2.w;
    b1[4] = (_Float16)w3.x; b1[5] = (_Float16)w3.y; b1[6] = (_Float16)w3.z; b1[7] = (_Float16)w3.w;
  }
  {
    _Float16* aw = As[0]; _Float16* bw = Bs[0];
    *(half8*)(aw + swz(ar, aku + 0) * 8) = a0;
    *(half8*)(aw + swz(ar, aku + 1) * 8) = a1;
    *(half8*)(aw + swz(ar, aku + 2) * 8) = a2;
    *(half8*)(aw + swz(ar, aku + 3) * 8) = a3;
    *(half8*)(bw + swz(br, bku + 0) * 8) = b0;
    *(half8*)(bw + swz(br, bku + 1) * 8) = b1;
  }
  __syncthreads();

  for (int kk = 0; kk < 8; ++kk) {
#pragma unroll
    for (int u = 0; u < 2; ++u) {
      int kc = kk * 2 + u;              // buf index u is compile-time
      if (kc < 15) {
        const _Float16* ap = abase + (kc + 1) * 64;
        const float*    wp = wbase + (kc + 1) * 64;
        a0 = *(const half8*)(ap);      a1 = *(const half8*)(ap + 8);
        a2 = *(const half8*)(ap + 16); a3 = *(const half8*)(ap + 24);
        float4 w0 = *(const float4*)(wp);      float4 w1 = *(const float4*)(wp + 4);
        float4 w2 = *(const float4*)(wp + 8);  float4 w3 = *(const float4*)(wp + 12);
        b0[0] = (_Float16)w0.x; b0[1] = (_Float16)w0.y; b0[2] = (_Float16)w0.z; b0[3] = (_Float16)w0.w;
        b0[4] = (_Float16)w1.x; b0[5] = (_Float16)w1.y; b0[6] = (_Float16)w1.z; b0[7] = (_Float16)w1.w;
        b1[0] = (_Float16)w2.x; b1[1] = (_Float16)w2.y; b1[2] = (_Float16)w2.z; b1[3] = (_Float16)w2.w;
        b1[4] = (_Float16)w3.x; b1[5] = (_Float16)w3.y; b1[6] = (_Float16)w3.z; b1[7] = (_Float16)w3.w;
      }

      const _Float16* ac = As[u];
      const _Float16* bc = Bs[u];
#pragma unroll
      for (int kh = 0; kh < 2; ++kh) {
        half8 Af[4], Bf[2];
#pragma unroll
        for (int mt = 0; mt < 4; ++mt)
          Af[mt] = *(const half8*)(ac + swz(mh + mt * 16 + l15, kh * 4 + quad) * 8);
#pragma unroll
        for (int nt = 0; nt < 2; ++nt)
          Bf[nt] = *(const half8*)(bc + swz(nh + nt * 16 + l15, kh * 4 + quad) * 8);
        __builtin_amdgcn_s_setprio(1);
#pragma unroll
        for (int mt = 0; mt < 4; ++mt)
#pragma unroll
          for (int nt = 0; nt < 2; ++nt)
            acc[mt][nt] = __builtin_amdgcn_mfma_f32_16x16x32_f16(Af[mt], Bf[nt], acc[mt][nt], 0, 0, 0);
        __builtin_amdgcn_s_setprio(0);
      }

      if (kc < 15) {
        _Float16* aw = As[u ^ 1]; _Float16* bw = Bs[u ^ 1];
        *(half8*)(aw + swz(ar, aku + 0) * 8) = a0;
        *(half8*)(aw + swz(ar, aku + 1) * 8) = a1;
        *(half8*)(aw + swz(ar, aku + 2) * 8) = a2;
        *(half8*)(aw + swz(ar, aku + 3) * 8) = a3;
        *(half8*)(bw + swz(br, bku + 0) * 8) = b0;
        *(half8*)(bw + swz(br, bku + 1) * 8) = b1;
      }
      __syncthreads();
    }
  }

#pragma unroll
  for (int mt = 0; mt < 4; ++mt)
#pragma unroll
    for (int nt = 0; nt < 2; ++nt)
#pragma unroll
      for (int reg = 0; reg < 4; ++reg) {
        int m = m0 + mh + mt * 16 + quad * 4 + reg;
        int n = n0 + nh + nt * 16 + l15;
        C[(size_t)m * DMODEL + n] = acc[mt][nt][reg];
      }
}

// ---------------------------------------------------------------------------
extern "C" void kernel_launch(void* const* d_in, const int* in_sizes, int n_in,
                              void* d_out, int out_size, void* d_ws, size_t ws_size,
                              hipStream_t stream) {
  const float* x    = (const float*)d_in[0];
  const float* pos  = (const float*)d_in[1];
  const float* Wm   = (const float*)d_in[2];
  const float* G    = (const float*)d_in[3];
  const float* Wout = (const float*)d_in[4];
  float* out = (float*)d_out;

  char* wsb = (char*)d_ws;
  float* masses = (float*)wsb;                                    // 256 KB
  unsigned short* invd = (unsigned short*)(wsb + (1 << 18));      // 8 MB
  _Float16* attnout = (_Float16*)(wsb + (1 << 18) + (8 << 20));   // 8 MB
  _Float16* xt      = (_Float16*)(wsb + (1 << 18) + (16 << 20));  // 8 MB

  prep_xt_masses<<<dim3(BATCH * NHEAD, 64), 256, 0, stream>>>(x, Wm, xt, masses);
  invdist_kernel<<<dim3(SEQ / 64, SEQ / 64), 256, 0, stream>>>(pos, invd);
  attn_mfma_kernel<<<dim3(BATCH * NHEAD * (SEQ / 64)), 256, 0, stream>>>(
      xt, masses, invd, G, attnout);
  out_gemm_mfma<<<dim3(DMODEL / 64, (BATCH * SEQ) / 128), 256, 0, stream>>>(
      attnout, Wout, out);
}

// Round 6
// 161.547 us; speedup vs baseline: 1.7631x; 1.7631x over previous
//
#include <hip/hip_runtime.h>
#include <hip/hip_bf16.h>

#define SEQ 2048
#define DMODEL 1024
#define NHEAD 16
#define HDIM 64
#define DPOS 64
#define BATCH 2

constexpr float EVENT_HORIZON = 1e-6f;
constexpr float MAX_FORCE = 50.0f;
constexpr float CURV = 0.15f;
constexpr float LOG2E = 1.44269504f;
// P = exp2(min(f,50)*log2e - S2), S2 = 39*log2e: e <= 2^15.87 = 59847 (fp16-safe),
// ratio-invariant under softmax normalization.
constexpr float SHIFT = 39.0f;

typedef __attribute__((ext_vector_type(8))) short frag8;        // 8 bf16/ushort
typedef __attribute__((ext_vector_type(4))) unsigned int uint4v;
typedef __attribute__((ext_vector_type(8))) _Float16 half8;     // 8 fp16
typedef __attribute__((ext_vector_type(2))) _Float16 half2t;    // 2 fp16
typedef __attribute__((ext_vector_type(4))) float frag4f;       // 4 fp32 (C/D)

union A8u { half8 v; half2t h[4]; };

__device__ inline short bfbits(float f) {
  __hip_bfloat16 h = __float2bfloat16(f);
  return *reinterpret_cast<short*>(&h);
}
__device__ inline float fbits(unsigned u) {
  union { unsigned u; float f; } c; c.u = u; return c.f;
}
__device__ inline half2t pkrtz(float a, float b) {
  return __builtin_bit_cast(half2t, __builtin_amdgcn_cvt_pkrtz(a, b));
}
// native 2^x, single v_exp_f32 (no hidden *log2e mul like __expf)
__device__ inline float exp2_fast(float x) {
  float r;
  asm("v_exp_f32 %0, %1" : "=v"(r) : "v"(x));
  return r;
}
// XOR swizzle in 16B units: row = 8 units (128B); b128 frag reads (fixed unit,
// 16 consecutive rows) and staging writes both cover banks <=2-way (free).
__device__ inline int swz(int row, int u) { return row * 8 + (u ^ (row & 7)); }

// ---------------------------------------------------------------------------
// Prep A (fused): transpose x -> xt[bh][d][j] fp16 AND masses[bh][s] =
// softplus(dot(x_row, W_mass[h])).
// ---------------------------------------------------------------------------
__global__ __launch_bounds__(256) void prep_xt_masses(
    const float* __restrict__ x, const float* __restrict__ Wm,
    _Float16* __restrict__ xt, float* __restrict__ masses) {
  int bh = blockIdx.x;           // b*16+h
  int h = bh & 15, b = bh >> 4;
  int t = threadIdx.x;
  int d = t & 63;
  int jg = (t >> 6) + (blockIdx.y << 2);   // j-group of 8, 0..255
  int j0 = jg * 8;
  const float* src = x + (size_t)(b * SEQ) * DMODEL + h * HDIM + d;
  float wmd = Wm[h * HDIM + d];
  half8 v;
  float fv[8];
#pragma unroll
  for (int jj = 0; jj < 8; ++jj) {
    float f = src[(size_t)(j0 + jj) * DMODEL];
    fv[jj] = f;
    v[jj] = (_Float16)f;
  }
  *(half8*)(xt + ((size_t)bh * HDIM + d) * SEQ + j0) = v;

  float msum = 0.f;
#pragma unroll
  for (int jj = 0; jj < 8; ++jj) {
    float s = fv[jj] * wmd;
#pragma unroll
    for (int off = 32; off; off >>= 1) s += __shfl_xor(s, off, 64);
    if (d == jj) msum = s;      // lane jj keeps row j0+jj's dot
  }
  if (d < 8) {
    float m = (msum > 20.f) ? msum : log1pf(expf(msum));
    masses[(size_t)bh * SEQ + j0 + d] = m;
  }
}

// ---------------------------------------------------------------------------
// Kernel 2: LDS-tiled distance kernel, bf16 output.
// ---------------------------------------------------------------------------
__global__ __launch_bounds__(256) void invdist_kernel(
    const float* __restrict__ pos, unsigned short* __restrict__ invd) {
  __shared__ float Li[64 * 68];
  __shared__ float Lj[64 * 68];
  int t = threadIdx.x;
  int i0 = blockIdx.y * 64, j0 = blockIdx.x * 64;

  int kk = (t & 15) * 4;
  int rr = t >> 4;
#pragma unroll
  for (int q = 0; q < 4; ++q) {
    int row = q * 16 + rr;
    float4 a = *(const float4*)(pos + (size_t)(i0 + row) * DPOS + kk);
    float4 b = *(const float4*)(pos + (size_t)(j0 + row) * DPOS + kk);
    Li[(kk + 0) * 68 + row] = a.x; Li[(kk + 1) * 68 + row] = a.y;
    Li[(kk + 2) * 68 + row] = a.z; Li[(kk + 3) * 68 + row] = a.w;
    Lj[(kk + 0) * 68 + row] = b.x; Lj[(kk + 1) * 68 + row] = b.y;
    Lj[(kk + 2) * 68 + row] = b.z; Lj[(kk + 3) * 68 + row] = b.w;
  }
  __syncthreads();

  int ti = (t >> 4) * 4;
  int tj = (t & 15) * 4;

  float acc[4][4];
#pragma unroll
  for (int a = 0; a < 4; ++a)
#pragma unroll
    for (int b = 0; b < 4; ++b) acc[a][b] = 0.f;

#pragma unroll 8
  for (int k = 0; k < 64; ++k) {
    float4 a = *(const float4*)(&Li[k * 68 + ti]);
    float4 b = *(const float4*)(&Lj[k * 68 + tj]);
    float av[4] = {a.x, a.y, a.z, a.w};
    float bv[4] = {b.x, b.y, b.z, b.w};
#pragma unroll
    for (int mi = 0; mi < 4; ++mi)
#pragma unroll
      for (int mj = 0; mj < 4; ++mj) {
        float d = av[mi] - bv[mj];
        acc[mi][mj] += d * d;
      }
  }

#pragma unroll
  for (int mi = 0; mi < 4; ++mi) {
    ushort4 o;
    unsigned short* op = (unsigned short*)&o;
#pragma unroll
    for (int mj = 0; mj < 4; ++mj) {
      float d2 = acc[mi][mj];
      float dn = sqrtf(d2 + EVENT_HORIZON);
      float w = d2 * (1.f + CURV * __cosf(dn));
      op[mj] = (unsigned short)bfbits(1.0f / fmaxf(w, EVENT_HORIZON));
    }
    *(ushort4*)(&invd[(size_t)(i0 + ti + mi) * SEQ + j0 + tj]) = o;
  }
}

// ---------------------------------------------------------------------------
// Kernel 3: fused gravitational attention, fp16 MFMA PV.
// r6 = r4 structure (256 thr = 4 waves x 16 i-rows, 64 i-rows/block, grid
// 1024 XCD-clustered, LDS masses broadcast) with the VGPR cap fixed:
// launch_bounds(256,4) -> cap 64 (empirical law: cap = 256/min_waves_per_EU;
// r4's (256,6) starved the allocator at 40 regs; r5's reg-masses then
// spilled catastrophically). Grid limits us to 4 blocks/CU = 4 waves/EU
// anyway, so min_waves=4 loses nothing. Chunk loop unrolled x2 so LDS
// buffer bases are compile-time.
// ---------------------------------------------------------------------------
__global__ __launch_bounds__(256, 4) void attn_mfma_kernel(
    const _Float16* __restrict__ xt, const float* __restrict__ masses,
    const unsigned short* __restrict__ invd, const float* __restrict__ G,
    _Float16* __restrict__ attnout) {
  __shared__ _Float16 Vs[2][64 * 64];   // [buf], 8 KB each, XOR-swizzled
  __shared__ float Ms[2][64];           // masses chunk broadcast

  constexpr float S2 = SHIFT * LOG2E;                 // 56.265
  constexpr float C2 = (MAX_FORCE - SHIFT) * LOG2E;   // 15.870

  int bid = blockIdx.x;
  int bh = (bid & 7) * 4 + ((bid >> 3) & 3);   // XCD-clustered: 4 bh per XCD
  int iblk = bid >> 5;
  int h = bh & (NHEAD - 1), b = bh >> 4;
  int i0 = iblk * 64;
  int t = threadIdx.x, w = t >> 6, lane = t & 63;
  int l15 = lane & 15, quad = lane >> 4;
  int iw = i0 + w * 16;

  float gabs = fabsf(G[h]);
  const float* mrow = masses + (size_t)bh * SEQ;
  float cm = gabs * mrow[iw + l15] * LOG2E;           // row scalar, log2 domain
  const unsigned short* ivrow = invd + (size_t)(iw + l15) * SEQ;

  // staging role: thread t -> d-row t>>2, 16B-units {2*(t&3), 2*(t&3)+1}
  int srow = t >> 2, sunit = (t & 3) * 2;
  const _Float16* srcrow =
      xt + ((size_t)bh * HDIM + srow) * SEQ + sunit * 8;
  int swzoff0 = swz(srow, sunit) * 8;
  int swzoff1 = swz(srow, sunit + 1) * 8;

  half8 vone;
#pragma unroll
  for (int k = 0; k < 8; ++k) vone[k] = (_Float16)1.f;

  frag4f acc[4];
#pragma unroll
  for (int nt = 0; nt < 4; ++nt) acc[nt] = (frag4f)0.f;
  frag4f accs = (frag4f)0.f;          // row sums (every column identical)

  // ---- prologue: chunk 0 ----
  *(half8*)(&Vs[0][0] + swzoff0) = *(const half8*)(srcrow);
  *(half8*)(&Vs[0][0] + swzoff1) = *(const half8*)(srcrow + 8);
  if (t < 64) Ms[0][t] = mrow[t];
  frag8 iv_cur[2], iv_nxt[2];
  iv_cur[0] = *(const frag8*)(ivrow + quad * 8);
  iv_cur[1] = *(const frag8*)(ivrow + 32 + quad * 8);
  __syncthreads();

  for (int cc = 0; cc < 16; ++cc) {
#pragma unroll
    for (int u = 0; u < 2; ++u) {
      int c = cc * 2 + u;               // buf index u is compile-time
      // ---- issue prefetches for chunk c+1 (latency hidden by compute) ----
      half8 vpre0, vpre1;
      float mload = 0.f;
      if (c < 31) {
        int jn = (c + 1) * 64;
        vpre0 = *(const half8*)(srcrow + jn);
        vpre1 = *(const half8*)(srcrow + jn + 8);
        if (t < 64) mload = mrow[jn + t];
        iv_nxt[0] = *(const frag8*)(ivrow + jn + quad * 8);
        iv_nxt[1] = *(const frag8*)(ivrow + jn + 32 + quad * 8);
      }

      // ---- compute chunk c from buf[u] ----
      const _Float16* Vbase = &Vs[u][0];
      const float* Mbase = &Ms[u][0];

#pragma unroll
      for (int kh = 0; kh < 2; ++kh) {
        // masses broadcast from LDS (same addr across l15 -> bank broadcast)
        const float* mp = Mbase + kh * 32 + quad * 8;
        float4 mjl = *(const float4*)(mp);
        float4 mjh = *(const float4*)(mp + 4);
        float mjf[8] = {mjl.x, mjl.y, mjl.z, mjl.w,
                        mjh.x, mjh.y, mjh.z, mjh.w};
        uint4v uv = __builtin_bit_cast(uint4v, iv_cur[kh]);
        float e[8];
#pragma unroll
        for (int p = 0; p < 4; ++p) {
          float ivA = fbits(uv[p] << 16);          // even j: low bf16
          float ivB = fbits(uv[p] & 0xffff0000u);  // odd j: high bf16
          float fA = fmaf(cm * mjf[2 * p], ivA, -S2);
          float fB = fmaf(cm * mjf[2 * p + 1], ivB, -S2);
          e[2 * p] = exp2_fast(fminf(fA, C2));
          e[2 * p + 1] = exp2_fast(fminf(fB, C2));
        }
        A8u A;
#pragma unroll
        for (int p = 0; p < 4; ++p)
          A.h[p] = pkrtz(e[2 * p], e[2 * p + 1]);

        __builtin_amdgcn_s_setprio(1);
        accs = __builtin_amdgcn_mfma_f32_16x16x32_f16(A.v, vone, accs, 0, 0, 0);
#pragma unroll
        for (int nt = 0; nt < 4; ++nt) {
          half8 Bf = *(const half8*)(Vbase + swz(nt * 16 + l15, kh * 4 + quad) * 8);
          acc[nt] = __builtin_amdgcn_mfma_f32_16x16x32_f16(A.v, Bf, acc[nt], 0, 0, 0);
        }
        __builtin_amdgcn_s_setprio(0);
      }

      // ---- rotate prefetches in; write V/M prefetch to other buffer ----
      if (c < 31) {
        _Float16* Vn = &Vs[u ^ 1][0];
        *(half8*)(Vn + swzoff0) = vpre0;
        *(half8*)(Vn + swzoff1) = vpre1;
        if (t < 64) Ms[u ^ 1][t] = mload;
        iv_cur[0] = iv_nxt[0]; iv_cur[1] = iv_nxt[1];
      }
      __syncthreads();
    }
  }

  // ---- normalize + store (accs[reg] already holds row r = quad*4+reg) ----
#pragma unroll
  for (int reg = 0; reg < 4; ++reg) {
    int r = quad * 4 + reg;            // C/D row within 16x16 tile
    float s = 1.f / accs[reg];
#pragma unroll
    for (int nt = 0; nt < 4; ++nt) {
      attnout[(size_t)(b * SEQ + iw + r) * DMODEL + h * HDIM + nt * 16 + l15] =
          (_Float16)(acc[nt][reg] * s);
    }
  }
}

// ---------------------------------------------------------------------------
// Kernel 4: out = attnout @ Wout^T via fp16 MFMA, Wout converted f32->fp16
// on the fly during B-staging (RTN scalar casts, numerically identical to
// the old prep_wh). 128(M)x64(N) tile, BK=64, double-buffered swizzled LDS,
// one barrier per K-chunk. grid (16,32) = 512 blocks.
// ---------------------------------------------------------------------------
__global__ __launch_bounds__(256) void out_gemm_mfma(
    const _Float16* __restrict__ Ag, const float* __restrict__ Wout,
    float* __restrict__ C) {
  __shared__ _Float16 As[2][128 * 64];   // 16 KB each
  __shared__ _Float16 Bs[2][64 * 64];    // 8 KB each

  int t = threadIdx.x, w = t >> 6, lane = t & 63;
  int l15 = lane & 15, quad = lane >> 4;
  int m0 = blockIdx.y * 128, n0 = blockIdx.x * 64;
  int mh = (w & 1) * 64, nh = (w >> 1) * 32;

  int ar = t >> 1;  int aku = (t & 1) * 4;
  int br = t >> 2;  int bku = (t & 3) * 2;
  const _Float16* abase = Ag + (size_t)(m0 + ar) * DMODEL + aku * 8;
  const float*    wbase = Wout + (size_t)(n0 + br) * DMODEL + bku * 8;

  frag4f acc[4][2];
#pragma unroll
  for (int mt = 0; mt < 4; ++mt)
#pragma unroll
    for (int nt = 0; nt < 2; ++nt) acc[mt][nt] = (frag4f)0.f;

  half8 a0, a1, a2, a3, b0, b1;
  a0 = *(const half8*)(abase);      a1 = *(const half8*)(abase + 8);
  a2 = *(const half8*)(abase + 16); a3 = *(const half8*)(abase + 24);
  {
    float4 w0 = *(const float4*)(wbase);      float4 w1 = *(const float4*)(wbase + 4);
    float4 w2 = *(const float4*)(wbase + 8);  float4 w3 = *(const float4*)(wbase + 12);
    b0[0] = (_Float16)w0.x; b0[1] = (_Float16)w0.y; b0[2] = (_Float16)w0.z; b0[3] = (_Float16)w0.w;
    b0[4] = (_Float16)w1.x; b0[5] = (_Float16)w1.y; b0[6] = (_Float16)w1.z; b0[7] = (_Float16)w1.w;
    b1[0] = (_Float16)w2.x; b1[1] = (_Float16)w2.y; b1[2] = (_Float16)w2.z; b1[3] = (_Float16)w2.w;
    b1[4] = (_Float16)w3.x; b1[5] = (_Float16)w3.y; b1[6] = (_Float16)w3.z; b1[7] = (_Float16)w3.w;
  }
  {
    _Float16* aw = As[0]; _Float16* bw = Bs[0];
    *(half8*)(aw + swz(ar, aku + 0) * 8) = a0;
    *(half8*)(aw + swz(ar, aku + 1) * 8) = a1;
    *(half8*)(aw + swz(ar, aku + 2) * 8) = a2;
    *(half8*)(aw + swz(ar, aku + 3) * 8) = a3;
    *(half8*)(bw + swz(br, bku + 0) * 8) = b0;
    *(half8*)(bw + swz(br, bku + 1) * 8) = b1;
  }
  __syncthreads();

  for (int kk = 0; kk < 8; ++kk) {
#pragma unroll
    for (int u = 0; u < 2; ++u) {
      int kc = kk * 2 + u;              // buf index u is compile-time
      if (kc < 15) {
        const _Float16* ap = abase + (kc + 1) * 64;
        const float*    wp = wbase + (kc + 1) * 64;
        a0 = *(const half8*)(ap);      a1 = *(const half8*)(ap + 8);
        a2 = *(const half8*)(ap + 16); a3 = *(const half8*)(ap + 24);
        float4 w0 = *(const float4*)(wp);      float4 w1 = *(const float4*)(wp + 4);
        float4 w2 = *(const float4*)(wp + 8);  float4 w3 = *(const float4*)(wp + 12);
        b0[0] = (_Float16)w0.x; b0[1] = (_Float16)w0.y; b0[2] = (_Float16)w0.z; b0[3] = (_Float16)w0.w;
        b0[4] = (_Float16)w1.x; b0[5] = (_Float16)w1.y; b0[6] = (_Float16)w1.z; b0[7] = (_Float16)w1.w;
        b1[0] = (_Float16)w2.x; b1[1] = (_Float16)w2.y; b1[2] = (_Float16)w2.z; b1[3] = (_Float16)w2.w;
        b1[4] = (_Float16)w3.x; b1[5] = (_Float16)w3.y; b1[6] = (_Float16)w3.z; b1[7] = (_Float16)w3.w;
      }

      const _Float16* ac = As[u];
      const _Float16* bc = Bs[u];
#pragma unroll
      for (int kh = 0; kh < 2; ++kh) {
        half8 Af[4], Bf[2];
#pragma unroll
        for (int mt = 0; mt < 4; ++mt)
          Af[mt] = *(const half8*)(ac + swz(mh + mt * 16 + l15, kh * 4 + quad) * 8);
#pragma unroll
        for (int nt = 0; nt < 2; ++nt)
          Bf[nt] = *(const half8*)(bc + swz(nh + nt * 16 + l15, kh * 4 + quad) * 8);
        __builtin_amdgcn_s_setprio(1);
#pragma unroll
        for (int mt = 0; mt < 4; ++mt)
#pragma unroll
          for (int nt = 0; nt < 2; ++nt)
            acc[mt][nt] = __builtin_amdgcn_mfma_f32_16x16x32_f16(Af[mt], Bf[nt], acc[mt][nt], 0, 0, 0);
        __builtin_amdgcn_s_setprio(0);
      }

      if (kc < 15) {
        _Float16* aw = As[u ^ 1]; _Float16* bw = Bs[u ^ 1];
        *(half8*)(aw + swz(ar, aku + 0) * 8) = a0;
        *(half8*)(aw + swz(ar, aku + 1) * 8) = a1;
        *(half8*)(aw + swz(ar, aku + 2) * 8) = a2;
        *(half8*)(aw + swz(ar, aku + 3) * 8) = a3;
        *(half8*)(bw + swz(br, bku + 0) * 8) = b0;
        *(half8*)(bw + swz(br, bku + 1) * 8) = b1;
      }
      __syncthreads();
    }
  }

#pragma unroll
  for (int mt = 0; mt < 4; ++mt)
#pragma unroll
    for (int nt = 0; nt < 2; ++nt)
#pragma unroll
      for (int reg = 0; reg < 4; ++reg) {
        int m = m0 + mh + mt * 16 + quad * 4 + reg;
        int n = n0 + nh + nt * 16 + l15;
        C[(size_t)m * DMODEL + n] = acc[mt][nt][reg];
      }
}

// ---------------------------------------------------------------------------
extern "C" void kernel_launch(void* const* d_in, const int* in_sizes, int n_in,
                              void* d_out, int out_size, void* d_ws, size_t ws_size,
                              hipStream_t stream) {
  const float* x    = (const float*)d_in[0];
  const float* pos  = (const float*)d_in[1];
  const float* Wm   = (const float*)d_in[2];
  const float* G    = (const float*)d_in[3];
  const float* Wout = (const float*)d_in[4];
  float* out = (float*)d_out;

  char* wsb = (char*)d_ws;
  float* masses = (float*)wsb;                                    // 256 KB
  unsigned short* invd = (unsigned short*)(wsb + (1 << 18));      // 8 MB
  _Float16* attnout = (_Float16*)(wsb + (1 << 18) + (8 << 20));   // 8 MB
  _Float16* xt      = (_Float16*)(wsb + (1 << 18) + (16 << 20));  // 8 MB

  prep_xt_masses<<<dim3(BATCH * NHEAD, 64), 256, 0, stream>>>(x, Wm, xt, masses);
  invdist_kernel<<<dim3(SEQ / 64, SEQ / 64), 256, 0, stream>>>(pos, invd);
  attn_mfma_kernel<<<dim3(BATCH * NHEAD * (SEQ / 64)), 256, 0, stream>>>(
      xt, masses, invd, G, attnout);
  out_gemm_mfma<<<dim3(DMODEL / 64, (BATCH * SEQ) / 128), 256, 0, stream>>>(
      attnout, Wout, out);
}